// Round 8
// baseline (274.721 us; speedup 1.0000x reference)
//
#include <hip/hip_runtime.h>
#include <cstdint>
#include <cstddef>

#define BB   4
#define AA   256
#define NNB  64
#define FF   128
#define NBAS 20
#define NLAY 3
#define BA   (BB*AA)        // 1024 atoms total
#define EDG  (BA*NNB)       // 65536 edges

typedef __attribute__((ext_vector_type(8))) short bf16x8;
typedef __attribute__((ext_vector_type(4))) float f32x4;

__device__ __forceinline__ float silu_f(float x){ return x / (1.0f + __expf(-x)); }

// round-to-nearest-even f32 -> bf16 bits
__device__ __forceinline__ unsigned short f2bf(float x){
  unsigned int u = __float_as_uint(x);
  u += 0x7FFFu + ((u >> 16) & 1u);
  return (unsigned short)(u >> 16);
}
__device__ __forceinline__ unsigned int pk2(float a, float b){
  return (unsigned int)f2bf(a) | ((unsigned int)f2bf(b) << 16);
}

// ------------- weight conversion: eqf_W1, eqf_W2, eme_W1, eme_W2 (+ padded me_W) ------------
__global__ void k_cvtw(const float* __restrict__ a, const float* __restrict__ b,
                       const float* __restrict__ c, const float* __restrict__ d,
                       const float* __restrict__ me, unsigned short* __restrict__ out){
  int id = blockIdx.x*256 + threadIdx.x;
  if (id < 196608){
    int reg = id / 49152, off = id - reg*49152;
    const float* src = (reg==0)?a:(reg==1)?b:(reg==2)?c:d;
    out[id] = f2bf(src[off]);
  } else if (id < 196608 + 12288){
    int p = id - 196608;
    int l = p >> 12;            // layer
    int rem = p & 4095;
    int row = rem >> 5, k = rem & 31;
    float v = (k < NBAS) ? me[((size_t)l*FF + row)*NBAS + k] : 0.0f;
    out[id] = f2bf(v);
  }
}

// ---------------- f32 two-pass MLP core over 16 rows ----------------
__device__ __forceinline__ void mlp16(const float (*xs)[FF], float (*hs)[FF], int o,
    const float* __restrict__ W1, const float* __restrict__ b1,
    const float* __restrict__ W2, const float* __restrict__ b2, float acc[16]){
  #pragma unroll
  for (int r=0;r<16;++r) acc[r] = b1[o];
  #pragma unroll
  for (int ic=0;ic<4;++ic){
    float4 wv[8];
    #pragma unroll
    for (int j=0;j<8;++j) wv[j] = *reinterpret_cast<const float4*>(&W1[(size_t)o*FF + ic*32 + j*4]);
    #pragma unroll
    for (int r=0;r<16;++r){
      #pragma unroll
      for (int j=0;j<8;++j){
        float4 xv = *reinterpret_cast<const float4*>(&xs[r][ic*32+j*4]);
        acc[r] = fmaf(xv.x, wv[j].x, acc[r]);
        acc[r] = fmaf(xv.y, wv[j].y, acc[r]);
        acc[r] = fmaf(xv.z, wv[j].z, acc[r]);
        acc[r] = fmaf(xv.w, wv[j].w, acc[r]);
      }
    }
  }
  #pragma unroll
  for (int r=0;r<16;++r) hs[r][o] = silu_f(acc[r]);
  __syncthreads();
  #pragma unroll
  for (int r=0;r<16;++r) acc[r] = b2[o];
  #pragma unroll
  for (int ic=0;ic<4;++ic){
    float4 wv[8];
    #pragma unroll
    for (int j=0;j<8;++j) wv[j] = *reinterpret_cast<const float4*>(&W2[(size_t)o*FF + ic*32 + j*4]);
    #pragma unroll
    for (int r=0;r<16;++r){
      #pragma unroll
      for (int j=0;j<8;++j){
        float4 xv = *reinterpret_cast<const float4*>(&hs[r][ic*32+j*4]);
        acc[r] = fmaf(xv.x, wv[j].x, acc[r]);
        acc[r] = fmaf(xv.y, wv[j].y, acc[r]);
        acc[r] = fmaf(xv.z, wv[j].z, acc[r]);
        acc[r] = fmaf(xv.w, wv[j].w, acc[r]);
      }
    }
  }
}

// ------- initial node kernel: emb gather + inv_node write + 3 node MLPs (layer 0) -------
__global__ __launch_bounds__(128) void k_node3_first(
    const int* __restrict__ z, const float* __restrict__ emb, float* __restrict__ inv_node,
    const float* W1a, const float* b1a, const float* W2a, const float* b2a, float* Ya,
    const float* W1b, const float* b1b, const float* W2b, const float* b2b, float* Yb,
    const float* W1c, const float* b1c, const float* W2c, const float* b2c, float* Yc){
  const float *W1,*b1,*W2,*b2; float* Y;
  if (blockIdx.y==0){ W1=W1a;b1=b1a;W2=W2a;b2=b2a;Y=Ya; }
  else if (blockIdx.y==1){ W1=W1b;b1=b1b;W2=W2b;b2=b2b;Y=Yb; }
  else { W1=W1c;b1=b1c;W2=W2c;b2=b2c;Y=Yc; }
  __shared__ __align__(16) float xs[16][FF];
  __shared__ __align__(16) float hs[16][FF];
  const int o = threadIdx.x;
  const int row0 = blockIdx.x * 16;
  #pragma unroll
  for (int r=0;r<16;++r){
    float v = emb[(size_t)z[row0+r]*FF + o];
    xs[r][o] = v;
    if (blockIdx.y==0) inv_node[(size_t)(row0+r)*FF + o] = v;
  }
  __syncthreads();
  float acc[16];
  mlp16(xs, hs, o, W1, b1, W2, b2, acc);
  #pragma unroll
  for (int r=0;r<16;++r) Y[(size_t)(row0+r)*FF + o] = acc[r];
}

// =====================================================================
// k_edge1: grid 512, 2 atoms (128 edges) per block.
//   phase A: inline geometry, me-MLP (MFMA swapped), inv_msg -> LDS,
//            scalg + eqF (absolute write on first).
//   phase B: X frags -> regs; W1eq staged -> GEMM1-eqf -> H1;
//            if (!first): W1me staged -> GEMM1-eme -> H2.
// =====================================================================
__global__ __launch_bounds__(256) void k_edge1(
    const float* __restrict__ dist, const float* __restrict__ dvec,
    const float* __restrict__ maskp, const int* __restrict__ nbrs,
    const float* __restrict__ msg_node,
    const unsigned short* __restrict__ meWb, const float* __restrict__ meb,
    const float* __restrict__ eqcW,
    const unsigned short* __restrict__ W1eq, const float* __restrict__ b1eq,
    const unsigned short* __restrict__ W1me,
    unsigned short* __restrict__ H1, unsigned short* __restrict__ H2,
    float* __restrict__ scalg, float* __restrict__ eqF, int first){
  __shared__ unsigned short Xs[128*136];
  __shared__ float eqFred[4][2][3];
  const int t = threadIdx.x, w = t>>6, l = t&63;
  const int bid = blockIdx.x, a0 = bid*2;
  const int g = l&15, kg = (l>>4)<<3, r0 = (l>>4)<<2;
  const float c5 = 0.6283185307179586f;      // pi/5

  #pragma unroll
  for (int p=0;p<2;++p){
    const int atom = a0 + p;
    const int eg = atom*NNB + w*16 + g;
    const float d = dist[eg];
    const float dinv = 1.0f/(d + 1e-8f);
    const float xx = d*0.2f;
    float x2=xx*xx, x4=x2*x2, x6=x4*x2, x7=x6*xx, x8=x7*xx;
    float ct = 1.0f - 28.0f*x6 + 48.0f*x7 - 21.0f*x8;
    ct = (xx < 1.0f) ? ct : 0.0f;
    bf16x8 rfr;
    #pragma unroll
    for (int i=0;i<8;++i){
      int k = kg + i;
      float v = (k < NBAS) ? __sinf((float)(k+1)*c5*d)*dinv : 0.0f;
      rfr[i] = (short)f2bf(v);
    }
    f32x4 acc[8];
    #pragma unroll
    for (int nt=0;nt<8;++nt){
      bf16x8 wfr = *(const bf16x8*)(meWb + (nt*16 + g)*32 + kg);
      acc[nt] = __builtin_amdgcn_mfma_f32_16x16x32_bf16(wfr, rfr, f32x4{0.f,0.f,0.f,0.f}, 0,0,0);
    }
    const int bbase = (atom/AA)*AA;
    const int nbv = bbase + nbrs[eg];
    float pv = 0.f;
    #pragma unroll
    for (int nt=0;nt<8;++nt){
      int o0 = nt*16 + r0;
      float4 mb = *(const float4*)(meb + o0);
      float4 mi = *(const float4*)(msg_node + (size_t)atom*FF + o0);
      float4 mf = *(const float4*)(msg_node + (size_t)nbv*FF + o0);
      float4 ec = *(const float4*)(eqcW + o0);
      float v0 = (acc[nt][0]+mb.x)*ct*mi.x*mf.x;
      float v1 = (acc[nt][1]+mb.y)*ct*mi.y*mf.y;
      float v2 = (acc[nt][2]+mb.z)*ct*mi.z*mf.z;
      float v3 = (acc[nt][3]+mb.w)*ct*mi.w*mf.w;
      pv = fmaf(v0,ec.x, fmaf(v1,ec.y, fmaf(v2,ec.z, fmaf(v3,ec.w, pv))));
      uint2 u; u.x = pk2(v0,v1); u.y = pk2(v2,v3);
      *(uint2*)(&Xs[(p*64 + w*16 + g)*136 + o0]) = u;
    }
    pv += __shfl_xor(pv,16); pv += __shfl_xor(pv,32);
    float cf0=0.f, cf1=0.f, cf2=0.f;
    if (l < 16){
      float m  = maskp[eg];
      float s0 = pv*dvec[(size_t)eg*3+0]*dinv;
      float s1 = pv*dvec[(size_t)eg*3+1]*dinv;
      float s2 = pv*dvec[(size_t)eg*3+2]*dinv;
      float4 sv; sv.x=s0; sv.y=s1; sv.z=s2; sv.w=m;
      *(float4*)(scalg + (size_t)eg*4) = sv;
      cf0 = s0*m; cf1 = s1*m; cf2 = s2*m;
    }
    #pragma unroll
    for (int s2=1; s2<16; s2<<=1){
      cf0 += __shfl_xor(cf0,s2); cf1 += __shfl_xor(cf1,s2); cf2 += __shfl_xor(cf2,s2);
    }
    if (l == 0){ eqFred[w][p][0]=cf0; eqFred[w][p][1]=cf1; eqFred[w][p][2]=cf2; }
  }
  __syncthreads();

  // X fragments -> registers; eq_F final write
  bf16x8 xf[2][4];
  #pragma unroll
  for (int ms=0;ms<2;++ms)
    #pragma unroll
    for (int ks=0;ks<4;++ks)
      xf[ms][ks] = *(const bf16x8*)(&Xs[(w*32 + ms*16 + g)*136 + ks*32 + kg]);
  if (t < 6){
    int p = t/3, c = t - p*3;
    float s = eqFred[0][p][c]+eqFred[1][p][c]+eqFred[2][p][c]+eqFred[3][p][c];
    eqF[(a0+p)*3 + c] = first ? s : (eqF[(a0+p)*3 + c] + s);
  }
  __syncthreads();

  // ---- stage W1eq into Xs; GEMM1-eqf -> H1 ----
  #pragma unroll
  for (int c=t; c<2048; c+=256){
    int row = c >> 4, ko = (c & 15) << 3;
    *(int4*)(&Xs[row*136 + ko]) = *(const int4*)(W1eq + row*FF + ko);
  }
  __syncthreads();
  f32x4 acc2[2][8];
  #pragma unroll
  for (int ms=0;ms<2;++ms)
    #pragma unroll
    for (int nt=0;nt<8;++nt) acc2[ms][nt] = f32x4{0.f,0.f,0.f,0.f};
  #pragma unroll
  for (int nt=0;nt<8;++nt)
    #pragma unroll
    for (int ks=0;ks<4;++ks){
      bf16x8 wfr = *(const bf16x8*)(&Xs[(nt*16+g)*136 + ks*32 + kg]);
      #pragma unroll
      for (int ms=0;ms<2;++ms)
        acc2[ms][nt] = __builtin_amdgcn_mfma_f32_16x16x32_bf16(wfr, xf[ms][ks], acc2[ms][nt], 0,0,0);
    }
  #pragma unroll
  for (int ms=0;ms<2;++ms)
    #pragma unroll
    for (int nt=0;nt<8;++nt){
      int o0 = nt*16 + r0;
      float4 bb = *(const float4*)(b1eq + o0);
      uint2 u;
      u.x = pk2(silu_f(acc2[ms][nt][0]+bb.x), silu_f(acc2[ms][nt][1]+bb.y));
      u.y = pk2(silu_f(acc2[ms][nt][2]+bb.z), silu_f(acc2[ms][nt][3]+bb.w));
      *(uint2*)(H1 + (size_t)(bid*128 + w*32 + ms*16 + g)*FF + o0) = u;
    }

  if (!first){
    __syncthreads();
    // ---- stage W1me into Xs; GEMM1-eme -> H2 ----
    #pragma unroll
    for (int c=t; c<2048; c+=256){
      int row = c >> 4, ko = (c & 15) << 3;
      *(int4*)(&Xs[row*136 + ko]) = *(const int4*)(W1me + row*FF + ko);
    }
    __syncthreads();
    #pragma unroll
    for (int ms=0;ms<2;++ms)
      #pragma unroll
      for (int nt=0;nt<8;++nt) acc2[ms][nt] = f32x4{0.f,0.f,0.f,0.f};
    #pragma unroll
    for (int nt=0;nt<8;++nt)
      #pragma unroll
      for (int ks=0;ks<4;++ks){
        bf16x8 wfr = *(const bf16x8*)(&Xs[(nt*16+g)*136 + ks*32 + kg]);
        #pragma unroll
        for (int ms=0;ms<2;++ms)
          acc2[ms][nt] = __builtin_amdgcn_mfma_f32_16x16x32_bf16(wfr, xf[ms][ks], acc2[ms][nt], 0,0,0);
      }
    #pragma unroll
    for (int ms=0;ms<2;++ms)
      #pragma unroll
      for (int nt=0;nt<8;++nt){
        int o0 = nt*16 + r0;
        uint2 u;
        u.x = pk2(silu_f(acc2[ms][nt][0]), silu_f(acc2[ms][nt][1]));
        u.y = pk2(silu_f(acc2[ms][nt][2]), silu_f(acc2[ms][nt][3]));
        *(uint2*)(H2 + (size_t)(bid*128 + w*32 + ms*16 + g)*FF + o0) = u;
      }
  }
}

// =====================================================================
// k_z: grid 1024 (one atom). GEMM2-eqf (+GEMM2-eme if !first) + reductions
// + merged finalize + (if !last) next-layer node-MLP epilogue.
// =====================================================================
__global__ __launch_bounds__(256) void k_z(
    const unsigned short* __restrict__ H1, const unsigned short* __restrict__ H2,
    const unsigned short* __restrict__ W2eq, const float* __restrict__ b2eq,
    const unsigned short* __restrict__ W2me,
    const float* __restrict__ scalg, const int* __restrict__ nbrs,
    const float* __restrict__ eqdrT_prev, float* __restrict__ eqdrT_next,
    float* __restrict__ esu_io, float* __restrict__ isu_io,
    float* __restrict__ eqf_out, float* __restrict__ eqdr,
    float* __restrict__ inv_node,
    const float* __restrict__ mnW1n, const float* __restrict__ mnb1n,
    const float* __restrict__ mnW2n, const float* __restrict__ mnb2n,
    float* __restrict__ msg_out,
    const float* __restrict__ esW1n, const float* __restrict__ esb1n,
    const float* __restrict__ esW2n, const float* __restrict__ esb2n,
    const float* __restrict__ isW1n, const float* __restrict__ isb1n,
    const float* __restrict__ isW2n, const float* __restrict__ isb2n,
    int first, int last){
  __shared__ unsigned short Wl[128*136];
  __shared__ float scal[64][4];
  __shared__ int   nbq[64];
  __shared__ float afl1[4][384];
  __shared__ float afl2[4][384];
  __shared__ __align__(16) float xs2[128];
  __shared__ __align__(16) float h_all[384];
  const int t = threadIdx.x, w = t>>6, l = t&63;
  const int atom = blockIdx.x;
  const int g = l&15, le = w*16 + g;
  const int kg = (l>>4)<<3, r0 = (l>>4)<<2;

  if (t < 64){
    float4 s = *(const float4*)(scalg + (size_t)(atom*NNB + t)*4);
    scal[t][0]=s.x; scal[t][1]=s.y; scal[t][2]=s.z; scal[t][3]=s.w;
    nbq[t] = (atom/AA)*AA + nbrs[atom*NNB + t];
  }
  bf16x8 hfr1[4];
  #pragma unroll
  for (int ks=0;ks<4;++ks)
    hfr1[ks] = *(const bf16x8*)(H1 + ((size_t)atom*NNB + le)*FF + ks*32 + kg);
  // ---- stage W2eq; GEMM2-eqf + masked scal reduce -> afl1 ----
  #pragma unroll
  for (int c=t; c<2048; c+=256){
    int row = c >> 4, ko = (c & 15) << 3;
    *(int4*)(&Wl[row*136 + ko]) = *(const int4*)(W2eq + row*FF + ko);
  }
  __syncthreads();
  f32x4 acc[8];
  #pragma unroll
  for (int nt=0;nt<8;++nt) acc[nt] = f32x4{0.f,0.f,0.f,0.f};
  #pragma unroll
  for (int nt=0;nt<8;++nt)
    #pragma unroll
    for (int ks=0;ks<4;++ks){
      bf16x8 wfr = *(const bf16x8*)(&Wl[(nt*16+g)*136 + ks*32 + kg]);
      acc[nt] = __builtin_amdgcn_mfma_f32_16x16x32_bf16(hfr1[ks], wfr, acc[nt], 0,0,0);
    }
  #pragma unroll
  for (int nt=0;nt<8;++nt){
    int col = nt*16 + g;
    float bb = b2eq[col];
    float q0=0.f,q1=0.f,q2=0.f;
    #pragma unroll
    for (int r=0;r<4;++r){
      int row = w*16 + r0 + r;
      float ym = (acc[nt][r] + bb) * scal[row][3];
      q0 = fmaf(ym, scal[row][0], q0);
      q1 = fmaf(ym, scal[row][1], q1);
      q2 = fmaf(ym, scal[row][2], q2);
    }
    q0 += __shfl_xor(q0,16); q0 += __shfl_xor(q0,32);
    q1 += __shfl_xor(q1,16); q1 += __shfl_xor(q1,32);
    q2 += __shfl_xor(q2,16); q2 += __shfl_xor(q2,32);
    if (l < 16){
      afl1[w][0*128+col] = q0; afl1[w][1*128+col] = q1; afl1[w][2*128+col] = q2;
    }
  }
  if (!first){
    bf16x8 hfr2[4];
    #pragma unroll
    for (int ks=0;ks<4;++ks)
      hfr2[ks] = *(const bf16x8*)(H2 + ((size_t)atom*NNB + le)*FF + ks*32 + kg);
    __syncthreads();
    // ---- stage W2me; GEMM2-eme + eqdrT_prev gather reduce -> afl2 ----
    #pragma unroll
    for (int c=t; c<2048; c+=256){
      int row = c >> 4, ko = (c & 15) << 3;
      *(int4*)(&Wl[row*136 + ko]) = *(const int4*)(W2me + row*FF + ko);
    }
    __syncthreads();
    #pragma unroll
    for (int nt=0;nt<8;++nt) acc[nt] = f32x4{0.f,0.f,0.f,0.f};
    #pragma unroll
    for (int nt=0;nt<8;++nt)
      #pragma unroll
      for (int ks=0;ks<4;++ks){
        bf16x8 wfr = *(const bf16x8*)(&Wl[(nt*16+g)*136 + ks*32 + kg]);
        acc[nt] = __builtin_amdgcn_mfma_f32_16x16x32_bf16(hfr2[ks], wfr, acc[nt], 0,0,0);
      }
    #pragma unroll
    for (int nt=0;nt<8;++nt){
      int col = nt*16 + g;
      float q0=0.f,q1=0.f,q2=0.f;
      #pragma unroll
      for (int r=0;r<4;++r){
        int row = w*16 + r0 + r;
        float ym = acc[nt][r] * scal[row][3];
        float4 gv = *(const float4*)(eqdrT_prev + ((size_t)nbq[row]*FF + col)*4);
        q0 = fmaf(ym, gv.x, q0);
        q1 = fmaf(ym, gv.y, q1);
        q2 = fmaf(ym, gv.z, q2);
      }
      q0 += __shfl_xor(q0,16); q0 += __shfl_xor(q0,32);
      q1 += __shfl_xor(q1,16); q1 += __shfl_xor(q1,32);
      q2 += __shfl_xor(q2,16); q2 += __shfl_xor(q2,32);
      if (l < 16){
        afl2[w][0*128+col] = q0; afl2[w][1*128+col] = q1; afl2[w][2*128+col] = q2;
      }
    }
  }
  __syncthreads();
  // ---- merged finalize ----
  for (int i=t; i<384; i+=256){
    int o = i & 127;
    float s1 = afl1[0][i]+afl1[1][i]+afl1[2][i]+afl1[3][i];
    float s2 = first ? 0.0f : (afl2[0][i]+afl2[1][i]+afl2[2][i]+afl2[3][i]);
    size_t idx = (size_t)atom*384 + i;
    float ef = first ? s1 : (eqf_out[idx] + s1);
    eqf_out[idx] = ef;
    float es = esu_io[(size_t)atom*FF + o];
    float v = (first ? 0.0f : eqdr[idx]) + s2 + es*s1;
    eqdr[idx] = v;
    eqdrT_next[((size_t)atom*FF + o)*4 + (i>>7)] = v;
    afl1[0][i] = ef * v;                       // reuse for cross-c sum
  }
  __syncthreads();
  if (t < 128){
    float sum3 = afl1[0][t] + afl1[0][128+t] + afl1[0][256+t];
    size_t idx = (size_t)atom*FF + t;
    float niv = fmaf(-isu_io[idx], sum3, inv_node[idx]);
    inv_node[idx] = niv;
    xs2[t] = niv;
  }
  __syncthreads();
  // ---- next-layer node MLPs (msg/esu/isu) from new inv_node ----
  if (!last){
    for (int idx = t; idx < 384; idx += 256){
      int m = idx >> 7, oo = idx & 127;
      const float* W1 = (m==0)? mnW1n : (m==1)? esW1n : isW1n;
      const float* b1 = (m==0)? mnb1n : (m==1)? esb1n : isb1n;
      float p = b1[oo];
      const float* wr = W1 + (size_t)oo*FF;
      #pragma unroll
      for (int k=0;k<FF;k+=4){
        float4 wv = *(const float4*)(wr+k);
        float4 xv = *(const float4*)(xs2+k);
        p = fmaf(wv.x,xv.x,p); p = fmaf(wv.y,xv.y,p);
        p = fmaf(wv.z,xv.z,p); p = fmaf(wv.w,xv.w,p);
      }
      h_all[idx] = silu_f(p);
    }
    __syncthreads();
    for (int idx = t; idx < 384; idx += 256){
      int m = idx >> 7, oo = idx & 127;
      const float* W2 = (m==0)? mnW2n : (m==1)? esW2n : isW2n;
      const float* b2 = (m==0)? mnb2n : (m==1)? esb2n : isb2n;
      float p = b2[oo];
      const float* wr = W2 + (size_t)oo*FF;
      const float* hh = h_all + (m<<7);
      #pragma unroll
      for (int k=0;k<FF;k+=4){
        float4 wv = *(const float4*)(wr+k);
        p = fmaf(wv.x,hh[k],p);   p = fmaf(wv.y,hh[k+1],p);
        p = fmaf(wv.z,hh[k+2],p); p = fmaf(wv.w,hh[k+3],p);
      }
      float* dst = (m==0)? msg_out : (m==1)? esu_io : isu_io;
      dst[(size_t)atom*FF + oo] = p;
    }
  }
}

extern "C" void kernel_launch(void* const* d_in, const int* in_sizes, int n_in,
                              void* d_out, int out_size, void* d_ws, size_t ws_size,
                              hipStream_t stream){
  const int*   z     = (const int*)  d_in[0];
  const int*   nbrs  = (const int*)  d_in[2];
  const float* maskp = (const float*)d_in[3];
  const float* dist  = (const float*)d_in[4];
  const float* dvec  = (const float*)d_in[5];
  const float* emb   = (const float*)d_in[6];
  const float* me_W  = (const float*)d_in[7];
  const float* me_b  = (const float*)d_in[8];
  const float* mn_W1 = (const float*)d_in[9];
  const float* mn_b1 = (const float*)d_in[10];
  const float* mn_W2 = (const float*)d_in[11];
  const float* mn_b2 = (const float*)d_in[12];
  const float* eqc_W = (const float*)d_in[13];
  const float* eqf_W1= (const float*)d_in[14];
  const float* eqf_b1= (const float*)d_in[15];
  const float* eqf_W2= (const float*)d_in[16];
  const float* eqf_b2= (const float*)d_in[17];
  const float* esu_W1= (const float*)d_in[18];
  const float* esu_b1= (const float*)d_in[19];
  const float* esu_W2= (const float*)d_in[20];
  const float* esu_b2= (const float*)d_in[21];
  const float* eme_W1= (const float*)d_in[22];
  const float* eme_W2= (const float*)d_in[23];
  const float* isu_W1= (const float*)d_in[24];
  const float* isu_b1= (const float*)d_in[25];
  const float* isu_W2= (const float*)d_in[26];
  const float* isu_b2= (const float*)d_in[27];

  float* out      = (float*)d_out;
  float* inv_node = out;                        // BA*FF   = 131072
  float* eqF      = out + 131072;               // BA*3    = 3072
  float* eqf      = out + 134144;               // BA*3*FF = 393216
  float* eqdr     = out + 527360;               // BA*3*FF = 393216

  // workspace layout (floats)
  float* w        = (float*)d_ws;
  float* msg_node = w;                          //   131,072
  float* esu_o    = w + 131072;                 //   131,072
  float* isu_o    = w + 262144;                 //   131,072
  float* scalg    = w + 393216;                 //   262,144 (EDG*4)
  float* eqdrT_A  = w + 655360;                 //   524,288 (BA*FF*4)
  float* eqdrT_B  = w + 1179648;                //   524,288
  unsigned short* wbf = (unsigned short*)(w + 1703936); // 208,896 us
  unsigned short* H1  = (unsigned short*)(w + 1808384); // EDG*FF us
  unsigned short* H2  = (unsigned short*)(w + 6002688); // EDG*FF us

  k_cvtw<<<817, 256, 0, stream>>>(eqf_W1, eqf_W2, eme_W1, eme_W2, me_W, wbf);
  k_node3_first<<<dim3(BA/16, 3), 128, 0, stream>>>(z, emb, inv_node,
      mn_W1,  mn_b1,  mn_W2,  mn_b2,  msg_node,
      esu_W1, esu_b1, esu_W2, esu_b2, esu_o,
      isu_W1, isu_b1, isu_W2, isu_b2, isu_o);

  for (int l=0; l<NLAY; ++l){
    size_t oB = (size_t)l*FF;
    const unsigned short* eqfW1b = wbf + 0*49152 + l*16384;
    const unsigned short* eqfW2b = wbf + 1*49152 + l*16384;
    const unsigned short* emeW1b = wbf + 2*49152 + l*16384;
    const unsigned short* emeW2b = wbf + 3*49152 + l*16384;
    const unsigned short* meWb   = wbf + 196608  + l*4096;
    float* dT_prev = (l & 1) ? eqdrT_B : eqdrT_A;
    float* dT_next = (l & 1) ? eqdrT_A : eqdrT_B;
    int ln = (l < NLAY-1) ? l+1 : l;            // next-layer weights (unused at last)
    size_t oWn = (size_t)ln*FF*FF, oBn = (size_t)ln*FF;
    int first = (l==0), last = (l==NLAY-1);

    k_edge1<<<BA/2, 256, 0, stream>>>(dist, dvec, maskp, nbrs, msg_node,
        meWb, me_b+oB, eqc_W+oB, eqfW1b, eqf_b1+oB, emeW1b,
        H1, H2, scalg, eqF, first);
    k_z<<<BA, 256, 0, stream>>>(H1, H2, eqfW2b, eqf_b2+oB, emeW2b,
        scalg, nbrs, dT_prev, dT_next, esu_o, isu_o,
        eqf, eqdr, inv_node,
        mn_W1+oWn,  mn_b1+oBn,  mn_W2+oWn,  mn_b2+oBn,  msg_node,
        esu_W1+oWn, esu_b1+oBn, esu_W2+oWn, esu_b2+oBn,
        isu_W1+oWn, isu_b1+oBn, isu_W2+oWn, isu_b2+oBn,
        first, last);
  }
}

// Round 9
// 234.176 us; speedup vs baseline: 1.1731x; 1.1731x over previous
//
#include <hip/hip_runtime.h>
#include <cstdint>
#include <cstddef>

#define BB   4
#define AA   256
#define NNB  64
#define FF   128
#define NBAS 20
#define NLAY 3
#define BA   (BB*AA)        // 1024 atoms total
#define EDG  (BA*NNB)       // 65536 edges

typedef __attribute__((ext_vector_type(8))) short bf16x8;
typedef __attribute__((ext_vector_type(4))) float f32x4;

__device__ __forceinline__ float silu_f(float x){ return x / (1.0f + __expf(-x)); }

// round-to-nearest-even f32 -> bf16 bits
__device__ __forceinline__ unsigned short f2bf(float x){
  unsigned int u = __float_as_uint(x);
  u += 0x7FFFu + ((u >> 16) & 1u);
  return (unsigned short)(u >> 16);
}
__device__ __forceinline__ unsigned int pk2(float a, float b){
  return (unsigned int)f2bf(a) | ((unsigned int)f2bf(b) << 16);
}

// ------------- weight conversion: eqf_W1, eqf_W2, eme_W1, eme_W2 (+ padded me_W) ------------
__global__ void k_cvtw(const float* __restrict__ a, const float* __restrict__ b,
                       const float* __restrict__ c, const float* __restrict__ d,
                       const float* __restrict__ me, unsigned short* __restrict__ out){
  int id = blockIdx.x*256 + threadIdx.x;
  if (id < 196608){
    int reg = id / 49152, off = id - reg*49152;
    const float* src = (reg==0)?a:(reg==1)?b:(reg==2)?c:d;
    out[id] = f2bf(src[off]);
  } else if (id < 196608 + 12288){
    int p = id - 196608;
    int l = p >> 12;            // layer
    int rem = p & 4095;
    int row = rem >> 5, k = rem & 31;
    float v = (k < NBAS) ? me[((size_t)l*FF + row)*NBAS + k] : 0.0f;
    out[id] = f2bf(v);
  }
}

// ---------------- f32 two-pass MLP core over 16 rows ----------------
__device__ __forceinline__ void mlp16(const float (*xs)[FF], float (*hs)[FF], int o,
    const float* __restrict__ W1, const float* __restrict__ b1,
    const float* __restrict__ W2, const float* __restrict__ b2, float acc[16]){
  #pragma unroll
  for (int r=0;r<16;++r) acc[r] = b1[o];
  #pragma unroll
  for (int ic=0;ic<4;++ic){
    float4 wv[8];
    #pragma unroll
    for (int j=0;j<8;++j) wv[j] = *reinterpret_cast<const float4*>(&W1[(size_t)o*FF + ic*32 + j*4]);
    #pragma unroll
    for (int r=0;r<16;++r){
      #pragma unroll
      for (int j=0;j<8;++j){
        float4 xv = *reinterpret_cast<const float4*>(&xs[r][ic*32+j*4]);
        acc[r] = fmaf(xv.x, wv[j].x, acc[r]);
        acc[r] = fmaf(xv.y, wv[j].y, acc[r]);
        acc[r] = fmaf(xv.z, wv[j].z, acc[r]);
        acc[r] = fmaf(xv.w, wv[j].w, acc[r]);
      }
    }
  }
  #pragma unroll
  for (int r=0;r<16;++r) hs[r][o] = silu_f(acc[r]);
  __syncthreads();
  #pragma unroll
  for (int r=0;r<16;++r) acc[r] = b2[o];
  #pragma unroll
  for (int ic=0;ic<4;++ic){
    float4 wv[8];
    #pragma unroll
    for (int j=0;j<8;++j) wv[j] = *reinterpret_cast<const float4*>(&W2[(size_t)o*FF + ic*32 + j*4]);
    #pragma unroll
    for (int r=0;r<16;++r){
      #pragma unroll
      for (int j=0;j<8;++j){
        float4 xv = *reinterpret_cast<const float4*>(&hs[r][ic*32+j*4]);
        acc[r] = fmaf(xv.x, wv[j].x, acc[r]);
        acc[r] = fmaf(xv.y, wv[j].y, acc[r]);
        acc[r] = fmaf(xv.z, wv[j].z, acc[r]);
        acc[r] = fmaf(xv.w, wv[j].w, acc[r]);
      }
    }
  }
}

// ------- initial node kernel: emb gather + inv_node write + 3 node MLPs (layer 0) -------
__global__ __launch_bounds__(128) void k_node3_first(
    const int* __restrict__ z, const float* __restrict__ emb, float* __restrict__ inv_node,
    const float* W1a, const float* b1a, const float* W2a, const float* b2a, float* Ya,
    const float* W1b, const float* b1b, const float* W2b, const float* b2b, float* Yb,
    const float* W1c, const float* b1c, const float* W2c, const float* b2c, float* Yc){
  const float *W1,*b1,*W2,*b2; float* Y;
  if (blockIdx.y==0){ W1=W1a;b1=b1a;W2=W2a;b2=b2a;Y=Ya; }
  else if (blockIdx.y==1){ W1=W1b;b1=b1b;W2=W2b;b2=b2b;Y=Yb; }
  else { W1=W1c;b1=b1c;W2=W2c;b2=b2c;Y=Yc; }
  __shared__ __align__(16) float xs[16][FF];
  __shared__ __align__(16) float hs[16][FF];
  const int o = threadIdx.x;
  const int row0 = blockIdx.x * 16;
  #pragma unroll
  for (int r=0;r<16;++r){
    float v = emb[(size_t)z[row0+r]*FF + o];
    xs[r][o] = v;
    if (blockIdx.y==0) inv_node[(size_t)(row0+r)*FF + o] = v;
  }
  __syncthreads();
  float acc[16];
  mlp16(xs, hs, o, W1, b1, W2, b2, acc);
  #pragma unroll
  for (int r=0;r<16;++r) Y[(size_t)(row0+r)*FF + o] = acc[r];
}

// ---------------- three node MLPs in one dispatch (layers 1,2) ----------------
__global__ __launch_bounds__(128) void k_mlp_node3(const float* __restrict__ X,
    const float* W1a, const float* b1a, const float* W2a, const float* b2a, float* Ya,
    const float* W1b, const float* b1b, const float* W2b, const float* b2b, float* Yb,
    const float* W1c, const float* b1c, const float* W2c, const float* b2c, float* Yc){
  const float *W1,*b1,*W2,*b2; float* Y;
  if (blockIdx.y==0){ W1=W1a;b1=b1a;W2=W2a;b2=b2a;Y=Ya; }
  else if (blockIdx.y==1){ W1=W1b;b1=b1b;W2=W2b;b2=b2b;Y=Yb; }
  else { W1=W1c;b1=b1c;W2=W2c;b2=b2c;Y=Yc; }
  __shared__ __align__(16) float xs[16][FF];
  __shared__ __align__(16) float hs[16][FF];
  const int o = threadIdx.x;
  const int row0 = blockIdx.x * 16;
  #pragma unroll
  for (int r=0;r<16;++r) xs[r][o] = X[(size_t)(row0+r)*FF + o];
  __syncthreads();
  float acc[16];
  mlp16(xs, hs, o, W1, b1, W2, b2, acc);
  #pragma unroll
  for (int r=0;r<16;++r) Y[(size_t)(row0+r)*FF + o] = acc[r];
}

// =====================================================================
// k_edge1: grid 512, 2 atoms (128 edges) per block.
//   phase A: inline geometry, me-MLP (MFMA swapped), inv_msg -> LDS,
//            scalg + eqF (absolute write on first).
//   phase B: X frags -> regs; W1eq staged -> GEMM1-eqf -> H1;
//            if (!first): W1me staged -> GEMM1-eme -> H2.
// =====================================================================
__global__ __launch_bounds__(256) void k_edge1(
    const float* __restrict__ dist, const float* __restrict__ dvec,
    const float* __restrict__ maskp, const int* __restrict__ nbrs,
    const float* __restrict__ msg_node,
    const unsigned short* __restrict__ meWb, const float* __restrict__ meb,
    const float* __restrict__ eqcW,
    const unsigned short* __restrict__ W1eq, const float* __restrict__ b1eq,
    const unsigned short* __restrict__ W1me,
    unsigned short* __restrict__ H1, unsigned short* __restrict__ H2,
    float* __restrict__ scalg, float* __restrict__ eqF, int first){
  __shared__ unsigned short Xs[128*136];
  __shared__ float eqFred[4][2][3];
  const int t = threadIdx.x, w = t>>6, l = t&63;
  const int bid = blockIdx.x, a0 = bid*2;
  const int g = l&15, kg = (l>>4)<<3, r0 = (l>>4)<<2;
  const float c5 = 0.6283185307179586f;      // pi/5

  #pragma unroll
  for (int p=0;p<2;++p){
    const int atom = a0 + p;
    const int eg = atom*NNB + w*16 + g;
    const float d = dist[eg];
    const float dinv = 1.0f/(d + 1e-8f);
    const float xx = d*0.2f;
    float x2=xx*xx, x4=x2*x2, x6=x4*x2, x7=x6*xx, x8=x7*xx;
    float ct = 1.0f - 28.0f*x6 + 48.0f*x7 - 21.0f*x8;
    ct = (xx < 1.0f) ? ct : 0.0f;
    bf16x8 rfr;
    #pragma unroll
    for (int i=0;i<8;++i){
      int k = kg + i;
      float v = (k < NBAS) ? __sinf((float)(k+1)*c5*d)*dinv : 0.0f;
      rfr[i] = (short)f2bf(v);
    }
    f32x4 acc[8];
    #pragma unroll
    for (int nt=0;nt<8;++nt){
      bf16x8 wfr = *(const bf16x8*)(meWb + (nt*16 + g)*32 + kg);
      acc[nt] = __builtin_amdgcn_mfma_f32_16x16x32_bf16(wfr, rfr, f32x4{0.f,0.f,0.f,0.f}, 0,0,0);
    }
    const int bbase = (atom/AA)*AA;
    const int nbv = bbase + nbrs[eg];
    float pv = 0.f;
    #pragma unroll
    for (int nt=0;nt<8;++nt){
      int o0 = nt*16 + r0;
      float4 mb = *(const float4*)(meb + o0);
      float4 mi = *(const float4*)(msg_node + (size_t)atom*FF + o0);
      float4 mf = *(const float4*)(msg_node + (size_t)nbv*FF + o0);
      float4 ec = *(const float4*)(eqcW + o0);
      float v0 = (acc[nt][0]+mb.x)*ct*mi.x*mf.x;
      float v1 = (acc[nt][1]+mb.y)*ct*mi.y*mf.y;
      float v2 = (acc[nt][2]+mb.z)*ct*mi.z*mf.z;
      float v3 = (acc[nt][3]+mb.w)*ct*mi.w*mf.w;
      pv = fmaf(v0,ec.x, fmaf(v1,ec.y, fmaf(v2,ec.z, fmaf(v3,ec.w, pv))));
      uint2 u; u.x = pk2(v0,v1); u.y = pk2(v2,v3);
      *(uint2*)(&Xs[(p*64 + w*16 + g)*136 + o0]) = u;
    }
    pv += __shfl_xor(pv,16); pv += __shfl_xor(pv,32);
    float cf0=0.f, cf1=0.f, cf2=0.f;
    if (l < 16){
      float m  = maskp[eg];
      float s0 = pv*dvec[(size_t)eg*3+0]*dinv;
      float s1 = pv*dvec[(size_t)eg*3+1]*dinv;
      float s2 = pv*dvec[(size_t)eg*3+2]*dinv;
      float4 sv; sv.x=s0; sv.y=s1; sv.z=s2; sv.w=m;
      *(float4*)(scalg + (size_t)eg*4) = sv;
      cf0 = s0*m; cf1 = s1*m; cf2 = s2*m;
    }
    #pragma unroll
    for (int s2=1; s2<16; s2<<=1){
      cf0 += __shfl_xor(cf0,s2); cf1 += __shfl_xor(cf1,s2); cf2 += __shfl_xor(cf2,s2);
    }
    if (l == 0){ eqFred[w][p][0]=cf0; eqFred[w][p][1]=cf1; eqFred[w][p][2]=cf2; }
  }
  __syncthreads();

  // X fragments -> registers; eq_F final write
  bf16x8 xf[2][4];
  #pragma unroll
  for (int ms=0;ms<2;++ms)
    #pragma unroll
    for (int ks=0;ks<4;++ks)
      xf[ms][ks] = *(const bf16x8*)(&Xs[(w*32 + ms*16 + g)*136 + ks*32 + kg]);
  if (t < 6){
    int p = t/3, c = t - p*3;
    float s = eqFred[0][p][c]+eqFred[1][p][c]+eqFred[2][p][c]+eqFred[3][p][c];
    eqF[(a0+p)*3 + c] = first ? s : (eqF[(a0+p)*3 + c] + s);
  }
  __syncthreads();

  // ---- stage W1eq into Xs; GEMM1-eqf -> H1 ----
  #pragma unroll
  for (int c=t; c<2048; c+=256){
    int row = c >> 4, ko = (c & 15) << 3;
    *(int4*)(&Xs[row*136 + ko]) = *(const int4*)(W1eq + row*FF + ko);
  }
  __syncthreads();
  f32x4 acc2[2][8];
  #pragma unroll
  for (int ms=0;ms<2;++ms)
    #pragma unroll
    for (int nt=0;nt<8;++nt) acc2[ms][nt] = f32x4{0.f,0.f,0.f,0.f};
  #pragma unroll
  for (int nt=0;nt<8;++nt)
    #pragma unroll
    for (int ks=0;ks<4;++ks){
      bf16x8 wfr = *(const bf16x8*)(&Xs[(nt*16+g)*136 + ks*32 + kg]);
      #pragma unroll
      for (int ms=0;ms<2;++ms)
        acc2[ms][nt] = __builtin_amdgcn_mfma_f32_16x16x32_bf16(wfr, xf[ms][ks], acc2[ms][nt], 0,0,0);
    }
  #pragma unroll
  for (int ms=0;ms<2;++ms)
    #pragma unroll
    for (int nt=0;nt<8;++nt){
      int o0 = nt*16 + r0;
      float4 bb = *(const float4*)(b1eq + o0);
      uint2 u;
      u.x = pk2(silu_f(acc2[ms][nt][0]+bb.x), silu_f(acc2[ms][nt][1]+bb.y));
      u.y = pk2(silu_f(acc2[ms][nt][2]+bb.z), silu_f(acc2[ms][nt][3]+bb.w));
      *(uint2*)(H1 + (size_t)(bid*128 + w*32 + ms*16 + g)*FF + o0) = u;
    }

  if (!first){
    __syncthreads();
    // ---- stage W1me into Xs; GEMM1-eme -> H2 ----
    #pragma unroll
    for (int c=t; c<2048; c+=256){
      int row = c >> 4, ko = (c & 15) << 3;
      *(int4*)(&Xs[row*136 + ko]) = *(const int4*)(W1me + row*FF + ko);
    }
    __syncthreads();
    #pragma unroll
    for (int ms=0;ms<2;++ms)
      #pragma unroll
      for (int nt=0;nt<8;++nt) acc2[ms][nt] = f32x4{0.f,0.f,0.f,0.f};
    #pragma unroll
    for (int nt=0;nt<8;++nt)
      #pragma unroll
      for (int ks=0;ks<4;++ks){
        bf16x8 wfr = *(const bf16x8*)(&Xs[(nt*16+g)*136 + ks*32 + kg]);
        #pragma unroll
        for (int ms=0;ms<2;++ms)
          acc2[ms][nt] = __builtin_amdgcn_mfma_f32_16x16x32_bf16(wfr, xf[ms][ks], acc2[ms][nt], 0,0,0);
      }
    #pragma unroll
    for (int ms=0;ms<2;++ms)
      #pragma unroll
      for (int nt=0;nt<8;++nt){
        int o0 = nt*16 + r0;
        uint2 u;
        u.x = pk2(silu_f(acc2[ms][nt][0]), silu_f(acc2[ms][nt][1]));
        u.y = pk2(silu_f(acc2[ms][nt][2]), silu_f(acc2[ms][nt][3]));
        *(uint2*)(H2 + (size_t)(bid*128 + w*32 + ms*16 + g)*FF + o0) = u;
      }
  }
}

// =====================================================================
// k_z: grid 1024 (one atom). GEMM2-eqf (+GEMM2-eme if !first) + reductions
// + merged finalize (eqf/eqdr/eqdrT/inv_node). Lean: no node-MLP epilogue.
// =====================================================================
__global__ __launch_bounds__(256) void k_z(
    const unsigned short* __restrict__ H1, const unsigned short* __restrict__ H2,
    const unsigned short* __restrict__ W2eq, const float* __restrict__ b2eq,
    const unsigned short* __restrict__ W2me,
    const float* __restrict__ scalg, const int* __restrict__ nbrs,
    const float* __restrict__ eqdrT_prev, float* __restrict__ eqdrT_next,
    const float* __restrict__ esu, const float* __restrict__ isu,
    float* __restrict__ eqf_out, float* __restrict__ eqdr,
    float* __restrict__ inv_node, int first){
  __shared__ unsigned short Wl[128*136];
  __shared__ float scal[64][4];
  __shared__ int   nbq[64];
  __shared__ float afl1[4][384];
  __shared__ float afl2[4][384];
  const int t = threadIdx.x, w = t>>6, l = t&63;
  const int atom = blockIdx.x;
  const int g = l&15, le = w*16 + g;
  const int kg = (l>>4)<<3, r0 = (l>>4)<<2;

  if (t < 64){
    float4 s = *(const float4*)(scalg + (size_t)(atom*NNB + t)*4);
    scal[t][0]=s.x; scal[t][1]=s.y; scal[t][2]=s.z; scal[t][3]=s.w;
    nbq[t] = (atom/AA)*AA + nbrs[atom*NNB + t];
  }
  bf16x8 hfr1[4];
  #pragma unroll
  for (int ks=0;ks<4;++ks)
    hfr1[ks] = *(const bf16x8*)(H1 + ((size_t)atom*NNB + le)*FF + ks*32 + kg);
  // ---- stage W2eq; GEMM2-eqf + masked scal reduce -> afl1 ----
  #pragma unroll
  for (int c=t; c<2048; c+=256){
    int row = c >> 4, ko = (c & 15) << 3;
    *(int4*)(&Wl[row*136 + ko]) = *(const int4*)(W2eq + row*FF + ko);
  }
  __syncthreads();
  f32x4 acc[8];
  #pragma unroll
  for (int nt=0;nt<8;++nt) acc[nt] = f32x4{0.f,0.f,0.f,0.f};
  #pragma unroll
  for (int nt=0;nt<8;++nt)
    #pragma unroll
    for (int ks=0;ks<4;++ks){
      bf16x8 wfr = *(const bf16x8*)(&Wl[(nt*16+g)*136 + ks*32 + kg]);
      acc[nt] = __builtin_amdgcn_mfma_f32_16x16x32_bf16(hfr1[ks], wfr, acc[nt], 0,0,0);
    }
  #pragma unroll
  for (int nt=0;nt<8;++nt){
    int col = nt*16 + g;
    float bb = b2eq[col];
    float q0=0.f,q1=0.f,q2=0.f;
    #pragma unroll
    for (int r=0;r<4;++r){
      int row = w*16 + r0 + r;
      float ym = (acc[nt][r] + bb) * scal[row][3];
      q0 = fmaf(ym, scal[row][0], q0);
      q1 = fmaf(ym, scal[row][1], q1);
      q2 = fmaf(ym, scal[row][2], q2);
    }
    q0 += __shfl_xor(q0,16); q0 += __shfl_xor(q0,32);
    q1 += __shfl_xor(q1,16); q1 += __shfl_xor(q1,32);
    q2 += __shfl_xor(q2,16); q2 += __shfl_xor(q2,32);
    if (l < 16){
      afl1[w][0*128+col] = q0; afl1[w][1*128+col] = q1; afl1[w][2*128+col] = q2;
    }
  }
  if (!first){
    bf16x8 hfr2[4];
    #pragma unroll
    for (int ks=0;ks<4;++ks)
      hfr2[ks] = *(const bf16x8*)(H2 + ((size_t)atom*NNB + le)*FF + ks*32 + kg);
    __syncthreads();
    // ---- stage W2me; GEMM2-eme + eqdrT_prev gather reduce -> afl2 ----
    #pragma unroll
    for (int c=t; c<2048; c+=256){
      int row = c >> 4, ko = (c & 15) << 3;
      *(int4*)(&Wl[row*136 + ko]) = *(const int4*)(W2me + row*FF + ko);
    }
    __syncthreads();
    #pragma unroll
    for (int nt=0;nt<8;++nt) acc[nt] = f32x4{0.f,0.f,0.f,0.f};
    #pragma unroll
    for (int nt=0;nt<8;++nt)
      #pragma unroll
      for (int ks=0;ks<4;++ks){
        bf16x8 wfr = *(const bf16x8*)(&Wl[(nt*16+g)*136 + ks*32 + kg]);
        acc[nt] = __builtin_amdgcn_mfma_f32_16x16x32_bf16(hfr2[ks], wfr, acc[nt], 0,0,0);
      }
    #pragma unroll
    for (int nt=0;nt<8;++nt){
      int col = nt*16 + g;
      float q0=0.f,q1=0.f,q2=0.f;
      #pragma unroll
      for (int r=0;r<4;++r){
        int row = w*16 + r0 + r;
        float ym = acc[nt][r] * scal[row][3];
        float4 gv = *(const float4*)(eqdrT_prev + ((size_t)nbq[row]*FF + col)*4);
        q0 = fmaf(ym, gv.x, q0);
        q1 = fmaf(ym, gv.y, q1);
        q2 = fmaf(ym, gv.z, q2);
      }
      q0 += __shfl_xor(q0,16); q0 += __shfl_xor(q0,32);
      q1 += __shfl_xor(q1,16); q1 += __shfl_xor(q1,32);
      q2 += __shfl_xor(q2,16); q2 += __shfl_xor(q2,32);
      if (l < 16){
        afl2[w][0*128+col] = q0; afl2[w][1*128+col] = q1; afl2[w][2*128+col] = q2;
      }
    }
  }
  __syncthreads();
  // ---- merged finalize ----
  for (int i=t; i<384; i+=256){
    int o = i & 127;
    float s1 = afl1[0][i]+afl1[1][i]+afl1[2][i]+afl1[3][i];
    float s2 = first ? 0.0f : (afl2[0][i]+afl2[1][i]+afl2[2][i]+afl2[3][i]);
    size_t idx = (size_t)atom*384 + i;
    float ef = first ? s1 : (eqf_out[idx] + s1);
    eqf_out[idx] = ef;
    float es = esu[(size_t)atom*FF + o];
    float v = (first ? 0.0f : eqdr[idx]) + s2 + es*s1;
    eqdr[idx] = v;
    eqdrT_next[((size_t)atom*FF + o)*4 + (i>>7)] = v;
    afl1[0][i] = ef * v;                       // reuse for cross-c sum
  }
  __syncthreads();
  if (t < 128){
    float sum3 = afl1[0][t] + afl1[0][128+t] + afl1[0][256+t];
    size_t idx = (size_t)atom*FF + t;
    inv_node[idx] = fmaf(-isu[idx], sum3, inv_node[idx]);
  }
}

extern "C" void kernel_launch(void* const* d_in, const int* in_sizes, int n_in,
                              void* d_out, int out_size, void* d_ws, size_t ws_size,
                              hipStream_t stream){
  const int*   z     = (const int*)  d_in[0];
  const int*   nbrs  = (const int*)  d_in[2];
  const float* maskp = (const float*)d_in[3];
  const float* dist  = (const float*)d_in[4];
  const float* dvec  = (const float*)d_in[5];
  const float* emb   = (const float*)d_in[6];
  const float* me_W  = (const float*)d_in[7];
  const float* me_b  = (const float*)d_in[8];
  const float* mn_W1 = (const float*)d_in[9];
  const float* mn_b1 = (const float*)d_in[10];
  const float* mn_W2 = (const float*)d_in[11];
  const float* mn_b2 = (const float*)d_in[12];
  const float* eqc_W = (const float*)d_in[13];
  const float* eqf_W1= (const float*)d_in[14];
  const float* eqf_b1= (const float*)d_in[15];
  const float* eqf_W2= (const float*)d_in[16];
  const float* eqf_b2= (const float*)d_in[17];
  const float* esu_W1= (const float*)d_in[18];
  const float* esu_b1= (const float*)d_in[19];
  const float* esu_W2= (const float*)d_in[20];
  const float* esu_b2= (const float*)d_in[21];
  const float* eme_W1= (const float*)d_in[22];
  const float* eme_W2= (const float*)d_in[23];
  const float* isu_W1= (const float*)d_in[24];
  const float* isu_b1= (const float*)d_in[25];
  const float* isu_W2= (const float*)d_in[26];
  const float* isu_b2= (const float*)d_in[27];

  float* out      = (float*)d_out;
  float* inv_node = out;                        // BA*FF   = 131072
  float* eqF      = out + 131072;               // BA*3    = 3072
  float* eqf      = out + 134144;               // BA*3*FF = 393216
  float* eqdr     = out + 527360;               // BA*3*FF = 393216

  // workspace layout (floats)
  float* w        = (float*)d_ws;
  float* msg_node = w;                          //   131,072
  float* esu_o    = w + 131072;                 //   131,072
  float* isu_o    = w + 262144;                 //   131,072
  float* scalg    = w + 393216;                 //   262,144 (EDG*4)
  float* eqdrT_A  = w + 655360;                 //   524,288 (BA*FF*4)
  float* eqdrT_B  = w + 1179648;                //   524,288
  unsigned short* wbf = (unsigned short*)(w + 1703936); // 208,896 us
  unsigned short* H1  = (unsigned short*)(w + 1808384); // EDG*FF us
  unsigned short* H2  = (unsigned short*)(w + 6002688); // EDG*FF us

  k_cvtw<<<817, 256, 0, stream>>>(eqf_W1, eqf_W2, eme_W1, eme_W2, me_W, wbf);
  k_node3_first<<<dim3(BA/16, 3), 128, 0, stream>>>(z, emb, inv_node,
      mn_W1,  mn_b1,  mn_W2,  mn_b2,  msg_node,
      esu_W1, esu_b1, esu_W2, esu_b2, esu_o,
      isu_W1, isu_b1, isu_W2, isu_b2, isu_o);

  for (int l=0; l<NLAY; ++l){
    size_t oB = (size_t)l*FF;
    const unsigned short* eqfW1b = wbf + 0*49152 + l*16384;
    const unsigned short* eqfW2b = wbf + 1*49152 + l*16384;
    const unsigned short* emeW1b = wbf + 2*49152 + l*16384;
    const unsigned short* emeW2b = wbf + 3*49152 + l*16384;
    const unsigned short* meWb   = wbf + 196608  + l*4096;
    float* dT_prev = (l & 1) ? eqdrT_B : eqdrT_A;   // unused at l==0 (first)
    float* dT_next = (l & 1) ? eqdrT_A : eqdrT_B;
    int first = (l==0);

    k_edge1<<<BA/2, 256, 0, stream>>>(dist, dvec, maskp, nbrs, msg_node,
        meWb, me_b+oB, eqc_W+oB, eqfW1b, eqf_b1+oB, emeW1b,
        H1, H2, scalg, eqF, first);
    k_z<<<BA, 256, 0, stream>>>(H1, H2, eqfW2b, eqf_b2+oB, emeW2b,
        scalg, nbrs, dT_prev, dT_next, esu_o, isu_o,
        eqf, eqdr, inv_node, first);
    if (l < NLAY-1){
      size_t oWn = (size_t)(l+1)*FF*FF, oBn = (size_t)(l+1)*FF;
      k_mlp_node3<<<dim3(BA/16, 3), 128, 0, stream>>>(inv_node,
          mn_W1+oWn,  mn_b1+oBn,  mn_W2+oWn,  mn_b2+oBn,  msg_node,
          esu_W1+oWn, esu_b1+oBn, esu_W2+oWn, esu_b2+oBn, esu_o,
          isu_W1+oWn, isu_b1+oBn, isu_W2+oWn, isu_b2+oBn, isu_o);
    }
  }
}